// Round 7
// baseline (174.971 us; speedup 1.0000x reference)
//
#include <hip/hip_runtime.h>
#include <math.h>

#define NPIX 4096
#define CH   256
#define CQD  32
#define LOG2E 1.44269504088896340736f

typedef float f32x4 __attribute__((ext_vector_type(4)));
typedef short s16x8 __attribute__((ext_vector_type(8)));

__device__ __forceinline__ unsigned short f2bf(float f) {
  unsigned u = __builtin_bit_cast(unsigned, f);
  return (unsigned short)((u + 0x7FFFu + ((u >> 16) & 1u)) >> 16);
}

// v_cvt_pk_bf16_f32: D[15:0]=bf16(a), D[31:16]=bf16(b)
__device__ __forceinline__ unsigned cvt_pk_bf16(float a, float b) {
  unsigned d;
  asm("v_cvt_pk_bf16_f32 %0, %1, %2" : "=v"(d) : "v"(a), "v"(b));
  return d;
}

__device__ __forceinline__ f32x4 mfma16(s16x8 a, s16x8 b, f32x4 c) {
  return __builtin_amdgcn_mfma_f32_16x16x32_bf16(a, b, c, 0, 0, 0);
}

__device__ __forceinline__ float fexp2(float x) {
#if __has_builtin(__builtin_amdgcn_exp2f)
  return __builtin_amdgcn_exp2f(x);
#else
  return exp2f(x);
#endif
}

__device__ __forceinline__ float frcp(float x) {
#if __has_builtin(__builtin_amdgcn_rcpf)
  return __builtin_amdgcn_rcpf(x);
#else
  return 1.0f / x;
#endif
}

// ---------------- Projection (W cvt fused; no wpack kernel) ----------------
// grid 512: b = blk>>7, 32-px tile p0 = (blk&127)*32.  512 thr / 8 waves, 2 blk/CU.
// Stage x[b][:, p0..p0+31] -> Xs[px][c] bf16.  Wave w owns d-tiles {w, 8+w}
// (+{16+w} if w<4), 16 out-ch each; W rows converted f32->bf16 inline (L2-hot).
// dt<4 (Q/K): mfma(X,W): D rows=px, cols=ch -> [px][ch] stores.
// dt>=4 (V) : mfma(W,X): D rows=ch, cols=px -> [ch][px] stores.
__global__ __launch_bounds__(512, 2) void proj_kernel(
    const float* __restrict__ x,
    const float* __restrict__ wq, const float* __restrict__ bq,
    const float* __restrict__ wk, const float* __restrict__ bk,
    const float* __restrict__ wv, const float* __restrict__ bv,
    unsigned short* __restrict__ Qb, unsigned short* __restrict__ Kb,
    unsigned short* __restrict__ Vb)
{
  __shared__ unsigned short Xs[32][264];   // 16.9 KB; 528B rows

  const int blk = blockIdx.x;
  const int b  = blk >> 7;
  const int p0 = (blk & 127) * 32;
  const int t = threadIdx.x;
  const int w = t >> 6;
  const int lane = t & 63;
  const int g = lane >> 4;
  const int r = lane & 15;

  // stage: thread t loads px = t&31, channel-quad (t>>5)*4 + 64*it
  {
    const int px = t & 31;
    const int cb = (t >> 5) * 4;
    const float* xb = x + (size_t)b * CH * NPIX + p0 + px;
    #pragma unroll
    for (int it = 0; it < 4; ++it) {
      const int c = cb + it * 64;
      const float f0 = xb[(size_t)(c + 0) * NPIX];
      const float f1 = xb[(size_t)(c + 1) * NPIX];
      const float f2 = xb[(size_t)(c + 2) * NPIX];
      const float f3 = xb[(size_t)(c + 3) * NPIX];
      uint2 pk;
      pk.x = cvt_pk_bf16(f0, f1);
      pk.y = cvt_pk_bf16(f2, f3);
      *(uint2*)&Xs[px][c] = pk;
    }
  }
  __syncthreads();

  const int ndd = (w < 4) ? 3 : 2;

  const float* wrow[3];
  float wscale[3];
  #pragma unroll
  for (int dd = 0; dd < 3; ++dd) {
    const int dt = w + dd * 8;
    if (dt < 2)      { wrow[dd] = wq + (size_t)(dt * 16 + r) * CH;       wscale[dd] = LOG2E; }
    else if (dt < 4) { wrow[dd] = wk + (size_t)((dt - 2) * 16 + r) * CH; wscale[dd] = 1.0f; }
    else             { wrow[dd] = wv + (size_t)((dt - 4) * 16 + r) * CH; wscale[dd] = 1.0f; }
  }

  f32x4 acc[3][2];
  #pragma unroll
  for (int dd = 0; dd < 3; ++dd)
    #pragma unroll
    for (int ps = 0; ps < 2; ++ps) { acc[dd][ps][0]=0.f; acc[dd][ps][1]=0.f; acc[dd][ps][2]=0.f; acc[dd][ps][3]=0.f; }

  #pragma unroll
  for (int kt = 0; kt < 8; ++kt) {
    const s16x8 xf0 = *(const s16x8*)&Xs[     r][kt * 32 + g * 8];
    const s16x8 xf1 = *(const s16x8*)&Xs[16 + r][kt * 32 + g * 8];
    #pragma unroll
    for (int dd = 0; dd < 3; ++dd) {
      if (dd >= ndd) continue;   // wave-uniform
      const int dt = w + dd * 8;
      const float4 wa = *(const float4*)&wrow[dd][kt * 32 + g * 8];
      const float4 wb = *(const float4*)&wrow[dd][kt * 32 + g * 8 + 4];
      const float s = wscale[dd];
      uint4 wu;
      wu.x = cvt_pk_bf16(wa.x * s, wa.y * s);
      wu.y = cvt_pk_bf16(wa.z * s, wa.w * s);
      wu.z = cvt_pk_bf16(wb.x * s, wb.y * s);
      wu.w = cvt_pk_bf16(wb.z * s, wb.w * s);
      const s16x8 wf = __builtin_bit_cast(s16x8, wu);
      if (dt < 4) {
        acc[dd][0] = mfma16(xf0, wf, acc[dd][0]);
        acc[dd][1] = mfma16(xf1, wf, acc[dd][1]);
      } else {
        acc[dd][0] = mfma16(wf, xf0, acc[dd][0]);
        acc[dd][1] = mfma16(wf, xf1, acc[dd][1]);
      }
    }
  }

  #pragma unroll
  for (int dd = 0; dd < 3; ++dd) {
    if (dd >= ndd) continue;
    const int dt = w + dd * 8;
    if (dt < 4) {
      // Q/K: lane (g,r), elem e: px = p0+ps*16+4g+e, out-ch = dloc + r
      const int dloc = (dt & 1) * 16;
      const float bias = (dt < 2) ? bq[dloc + r] * LOG2E : bk[dloc + r];
      unsigned short* dst = (dt < 2) ? Qb : Kb;
      #pragma unroll
      for (int ps = 0; ps < 2; ++ps)
        #pragma unroll
        for (int e = 0; e < 4; ++e) {
          const int px = p0 + ps * 16 + 4 * g + e;
          dst[((size_t)b * NPIX + px) * CQD + dloc + r] = f2bf(acc[dd][ps][e] + bias);
        }
    } else {
      // V: lane (g,r), elem e: ch = (dt-4)*16+4g+e, px = p0+ps*16+r
      const int c0v = (dt - 4) * 16;
      const float4 b4 = *(const float4*)&bv[c0v + 4 * g];
      #pragma unroll
      for (int ps = 0; ps < 2; ++ps) {
        const int px = p0 + ps * 16 + r;
        Vb[((size_t)b * CH + c0v + 4 * g + 0) * NPIX + px] = f2bf(acc[dd][ps][0] + b4.x);
        Vb[((size_t)b * CH + c0v + 4 * g + 1) * NPIX + px] = f2bf(acc[dd][ps][1] + b4.y);
        Vb[((size_t)b * CH + c0v + 4 * g + 2) * NPIX + px] = f2bf(acc[dd][ps][2] + b4.z);
        Vb[((size_t)b * CH + c0v + 4 * g + 3) * NPIX + px] = f2bf(acc[dd][ps][3] + b4.w);
      }
    }
  }
}

// ---------------- Flash attention + residual ----------------
// grid 512: xcd=blk&7 -> b=xcd>>1, split=xcd&1; i0=(blk>>3)*64 (QBLK=64).
// Swapped QK (mfma(K,Q): D rows=j cols=i) -> cvt_pk -> one b64 LDS write/i-sub.
// Swapped PV (mfma(V,P): D rows=ch cols=i) -> direct coalesced epilogue.
// Ps XOR-SWIZZLED (T2/m201): byte = row*128 + (2j ^ ((row&7)<<4)); row stride
// 128B; spreads the b128 P-frag reads (16 rows x 4 col-slots) across all 8
// 16B slots -> conflict-free per m201's measured distribution.
__global__ __launch_bounds__(256, 2) void attn_kernel(
    const unsigned short* __restrict__ Qb, const unsigned short* __restrict__ Kb,
    const unsigned short* __restrict__ Vb, const float* __restrict__ x,
    const float* __restrict__ gamma, float* __restrict__ out)
{
  __shared__ __align__(16) unsigned char PsRaw[2][64 * 128];  // 16 KB
  __shared__ float l_s[64];

  const int blk = blockIdx.x;
  const int xcd = blk & 7;
  const int b = xcd >> 1;
  const int split = xcd & 1;
  const int i0 = (blk >> 3) * 64;

  const int tid = threadIdx.x;
  const int w = tid >> 6;
  const int lane = tid & 63;
  const int g = lane >> 4;
  const int r = lane & 15;
  const int c0 = split * 128 + w * 32;
  const int xr = (r & 7) << 4;            // swizzle term (row&7 == r&7 here)

  const unsigned short* __restrict__ Qbase = Qb + (size_t)b * NPIX * CQD;
  const unsigned short* __restrict__ Kbase = Kb + (size_t)b * NPIX * CQD;
  const unsigned short* __restrict__ Vbase = Vb + (size_t)b * CH * NPIX;

  // Q B-frags: lane r = i-col, 4 i-subs (hoisted for all tiles)
  s16x8 qf[4];
  #pragma unroll
  for (int is = 0; is < 4; ++is)
    qf[is] = *(const s16x8*)&Qbase[(size_t)(i0 + is * 16 + r) * CQD + g * 8];

  s16x8 ones;
  #pragma unroll
  for (int j = 0; j < 8; ++j) ones[j] = (short)0x3F80;  // bf16 1.0

  f32x4 o[4][2];   // [i-sub][ch-sub]
  f32x4 o_l = {0.f, 0.f, 0.f, 0.f};
  #pragma unroll
  for (int is = 0; is < 4; ++is)
    #pragma unroll
    for (int cs = 0; cs < 2; ++cs) { o[is][cs][0]=0.f; o[is][cs][1]=0.f; o[is][cs][2]=0.f; o[is][cs][3]=0.f; }

  // tile-0 prefetch
  s16x8 kf = *(const s16x8*)&Kbase[(size_t)(w * 16 + r) * CQD + g * 8];
  s16x8 vf[2][2];
  #pragma unroll
  for (int cs = 0; cs < 2; ++cs)
    #pragma unroll
    for (int ks = 0; ks < 2; ++ks)
      vf[cs][ks] = *(const s16x8*)&Vbase[(size_t)(c0 + cs * 16 + r) * NPIX + ks * 32 + g * 8];

  #pragma unroll 2
  for (int t = 0; t < 64; ++t) {
    const int cur = t & 1;
    const f32x4 z = {0.f, 0.f, 0.f, 0.f};

    // S^T tile: D rows = j (w*16+4g+e), cols = i (is*16+r)
    f32x4 s[4];
    #pragma unroll
    for (int is = 0; is < 4; ++is) s[is] = mfma16(kf, qf[is], z);

    // prefetch next tile (drained at this iteration's barrier; used next iter)
    const int jn = ((t + 1) & 63) * 64;
    const s16x8 nkf = *(const s16x8*)&Kbase[(size_t)(jn + w * 16 + r) * CQD + g * 8];
    s16x8 nvf[2][2];
    #pragma unroll
    for (int cs = 0; cs < 2; ++cs)
      #pragma unroll
      for (int ks = 0; ks < 2; ++ks)
        nvf[cs][ks] = *(const s16x8*)&Vbase[(size_t)(c0 + cs * 16 + r) * NPIX + jn + ks * 32 + g * 8];

    // P = exp2(S) -> packed bf16 -> one swizzled b64 LDS write per i-sub
    #pragma unroll
    for (int is = 0; is < 4; ++is) {
      const float p0v = fexp2(s[is][0]);
      const float p1v = fexp2(s[is][1]);
      const float p2v = fexp2(s[is][2]);
      const float p3v = fexp2(s[is][3]);
      uint2 pk;
      pk.x = cvt_pk_bf16(p0v, p1v);
      pk.y = cvt_pk_bf16(p2v, p3v);
      *(uint2*)&PsRaw[cur][(16 * is + r) * 128 + ((32 * w + 8 * g) ^ xr)] = pk;
    }

    __syncthreads();

    // PV: O[ch][i] += V[ch][j] P^T[j][i]  (swizzled b128 P-frag reads)
    #pragma unroll
    for (int is = 0; is < 4; ++is) {
      const unsigned char* pr = &PsRaw[cur][(16 * is + r) * 128];
      const s16x8 pb0 = *(const s16x8*)(pr + ((16 * g) ^ xr));
      const s16x8 pb1 = *(const s16x8*)(pr + ((64 + 16 * g) ^ xr));
      o[is][0] = mfma16(vf[0][0], pb0, o[is][0]);
      o[is][0] = mfma16(vf[0][1], pb1, o[is][0]);
      o[is][1] = mfma16(vf[1][0], pb0, o[is][1]);
      o[is][1] = mfma16(vf[1][1], pb1, o[is][1]);
      if (is == w) {  // row-sums for i-sub w (all D rows equal)
        o_l = mfma16(ones, pb0, o_l);
        o_l = mfma16(ones, pb1, o_l);
      }
    }

    kf = nkf;
    #pragma unroll
    for (int cs = 0; cs < 2; ++cs)
      #pragma unroll
      for (int ks = 0; ks < 2; ++ks) vf[cs][ks] = nvf[cs][ks];
  }

  // publish l: wave w holds l for i = w*16 + r (cols), any row elem
  if (g == 0) l_s[w * 16 + r] = o_l[0];
  __syncthreads();

  float rl[4];
  #pragma unroll
  for (int is = 0; is < 4; ++is) rl[is] = frcp(l_s[is * 16 + r]);

  const float gam = gamma[0];
  #pragma unroll
  for (int is = 0; is < 4; ++is)
    #pragma unroll
    for (int cs = 0; cs < 2; ++cs)
      #pragma unroll
      for (int e = 0; e < 4; ++e) {
        const int ch = c0 + cs * 16 + 4 * g + e;
        const size_t off = ((size_t)b * CH + ch) * NPIX + i0 + is * 16 + r;
        out[off] = gam * o[is][cs][e] * rl[is] + x[off];
      }
}

extern "C" void kernel_launch(void* const* d_in, const int* in_sizes, int n_in,
                              void* d_out, int out_size, void* d_ws, size_t ws_size,
                              hipStream_t stream) {
  const float* x     = (const float*)d_in[0];
  const float* wq    = (const float*)d_in[1];
  const float* bq    = (const float*)d_in[2];
  const float* wk    = (const float*)d_in[3];
  const float* bk    = (const float*)d_in[4];
  const float* wv    = (const float*)d_in[5];
  const float* bv    = (const float*)d_in[6];
  const float* gamma = (const float*)d_in[7];
  float* out = (float*)d_out;

  // ws: Qb 1MB | Kb 1MB | Vb 8MB  (~10 MB)
  unsigned short* Qb = (unsigned short*)d_ws;
  unsigned short* Kb = Qb + (size_t)4 * NPIX * CQD;
  unsigned short* Vb = Kb + (size_t)4 * NPIX * CQD;

  hipLaunchKernelGGL(proj_kernel, dim3(512), dim3(512), 0, stream,
                     x, wq, bq, wk, bk, wv, bv, Qb, Kb, Vb);
  hipLaunchKernelGGL(attn_kernel, dim3(512), dim3(256), 0, stream,
                     Qb, Kb, Vb, x, gamma, out);
}